// Round 8
// baseline (2710.296 us; speedup 1.0000x reference)
//
#include <hip/hip_runtime.h>
#include <math.h>

#define S 32
#define T 32
#define B 64
#define H 256
#define MSZ 65536   // elements per swizzled bf16 matrix [8 kt][256 col][32 kk]
#define ROWSP 16
#define FPAD 8      // ints per flag slot (32 B)

typedef __attribute__((ext_vector_type(8))) short s16x8;
typedef __attribute__((ext_vector_type(4))) float f32x4;

__device__ inline unsigned short f2b(float f){
    unsigned u = __builtin_bit_cast(unsigned, f);
    u += 0x7fffu + ((u >> 16) & 1u);          // RNE
    return (unsigned short)(u >> 16);
}
__device__ inline float b2f(unsigned short s){
    unsigned u = ((unsigned)s) << 16;
    return __builtin_bit_cast(float, u);
}
__device__ inline float tanh_fast(float x){
    float e = __builtin_amdgcn_exp2f(x * 2.8853900817779268f);
    float r = __builtin_amdgcn_rcpf(e + 1.0f);
    return fmaf(-2.0f, r, 1.0f);
}
// wave-uniform poll: wait until *f != 0
__device__ inline void pollflag(const int* f){
    while (__hip_atomic_load(f, __ATOMIC_RELAXED, __HIP_MEMORY_SCOPE_AGENT) == 0)
        __builtin_amdgcn_s_sleep(1);
    asm volatile("" ::: "memory");
}
// A fragment from row-major f32 (fallback path only)
__device__ inline s16x8 make_afrag(const float* __restrict__ M, int arow, int k0){
    const float* p = M + arow * H + k0;
    float4 x = *(const float4*)(p);
    float4 y = *(const float4*)(p + 4);
    s16x8 r;
    r[0]=(short)f2b(x.x); r[1]=(short)f2b(x.y); r[2]=(short)f2b(x.z); r[3]=(short)f2b(x.w);
    r[4]=(short)f2b(y.x); r[5]=(short)f2b(y.y); r[6]=(short)f2b(y.z); r[7]=(short)f2b(y.w);
    return r;
}

// ---------------- prep: swizzle U (both depths, top/left) + W[1] to bf16 ----
// Bsw[m][kt][c][kk] = M_m[kt*32+kk][c];  m: 0=U0t 1=U0l 2=U1t 3=U1l 4=W1
__global__ __launch_bounds__(256) void prep_kernel(
    const float* __restrict__ U, const float* __restrict__ W,
    unsigned short* __restrict__ Bsw)
{
    int t = blockIdx.x * 256 + threadIdx.x;
    if (t >= 5 * MSZ) return;
    int m  = t >> 16;
    int r  = t & 65535;
    int kt = r >> 13;
    int r2 = r & 8191;
    int c  = r2 >> 5;
    int kk = r2 & 31;
    int krow = kt * 32 + kk;
    float v;
    if (m < 4){ int d = m >> 1, ope = m & 1; v = U[((size_t)d*2*H + ope*H + krow)*H + c]; }
    else      { v = W[((size_t)H + krow)*H + c]; }   // W[1]
    Bsw[t] = f2b(v);
}

// ---------------- depth-0 projections (bf16 out): sxw = src@W0, tyw = trg@W0
__global__ __launch_bounds__(256) void proj0b_kernel(
    const float* __restrict__ src, const float* __restrict__ trg,
    const float* __restrict__ W0, unsigned short* __restrict__ sxw,
    unsigned short* __restrict__ tyw)
{
    const int c = threadIdx.x;
    int gr0 = blockIdx.x * ROWSP;
    const float* inp; unsigned short* outp; int r0;
    if (gr0 < S * B) { inp = src; outp = sxw; r0 = gr0; }
    else             { inp = trg; outp = tyw; r0 = gr0 - S * B; }

    float acc[ROWSP];
#pragma unroll
    for (int rr = 0; rr < ROWSP; ++rr) acc[rr] = 0.f;
    for (int k = 0; k < H; ++k) {
        float wv = W0[k * H + c];
#pragma unroll
        for (int rr = 0; rr < ROWSP; ++rr)
            acc[rr] = fmaf(inp[(size_t)(r0 + rr) * H + k], wv, acc[rr]);
    }
#pragma unroll
    for (int rr = 0; rr < ROWSP; ++rr)
        outp[(size_t)(r0 + rr) * H + c] = f2b(acc[rr]);
}

__global__ __launch_bounds__(256) void zeroflags_kernel(int* flags, int n){
    int t = blockIdx.x * 256 + threadIdx.x;
    if (t < n) flags[t] = 0;
}

// ---------------- persistent dataflow, 3 block types ----------------
// 96 blocks x 512 thr: 0..31 d0 row i; 32..63 d1 row i; 64..95 proj row i.
// Chains: d0/d1 bodies = 128 MFMAs + epilogue, top prefetched 1 col ahead.
// proj blocks (no self-chain): poll f0 -> px=hx0@W1, py=hy0@W1 -> g.
// LDS 64KB: [0,32K) left hx persist; [32K,64K) top staging (or hy0 for proj).
__global__ __launch_bounds__(512, 1) void grid_kernel(
    const unsigned short* __restrict__ Bsw,
    const unsigned short* __restrict__ sxwb,
    const unsigned short* __restrict__ tywb,
    const float* __restrict__ bvec,
    float* __restrict__ out,
    int* __restrict__ flags)
{
    __shared__ char lds[65536];

    const int blk  = blockIdx.x;
    const int btyp = blk >> 5;          // 0=d0, 1=d1, 2=proj
    const int i    = blk & 31;

    const int tid  = threadIdx.x;
    const int lane = tid & 63;
    const int wv   = tid >> 6;
    const int colq = lane & 15;
    const int hi   = lane >> 4;
    const int kk0  = hi * 8;
    const int hi16 = hi * 16;
    const int lswz = (colq & 7) << 4;
    const int c0   = wv * 32 + colq;    // col for ct=0; ct=1 -> +16

    const int srow = tid >> 3;          // staging row 0..63
    const int cb   = (tid & 7) * 32;    // staging col base (32 f32)
    const int swzS = (srow & 7) << 4;

    int* f0 = flags;
    int* gg = flags + S*T*FPAD;
    int* f1 = flags + 2*S*T*FPAD;

    const size_t CH_ = (size_t)B * H;
#define OPTR(dd,ii,jj,cc) (out + ((((size_t)(dd)*S + (ii))*T + (jj))*2 + (cc)) * CH_)

#define LOADR(Lr, SP) do { \
    const float* _p = (SP) + (size_t)srow * H + cb; \
    _Pragma("unroll") \
    for (int _l = 0; _l < 4; ++_l) { \
        (Lr)[2*_l]   = *(const float4*)(_p + _l*8); \
        (Lr)[2*_l+1] = *(const float4*)(_p + _l*8 + 4); \
    } } while(0)

#define WRITR(BASE, Lr) do { \
    _Pragma("unroll") \
    for (int _l = 0; _l < 4; ++_l) { \
        float4 _a = (Lr)[2*_l], _b = (Lr)[2*_l+1]; \
        uint4 _g; \
        _g.x = f2b(_a.x) | ((unsigned)f2b(_a.y) << 16); \
        _g.y = f2b(_a.z) | ((unsigned)f2b(_a.w) << 16); \
        _g.z = f2b(_b.x) | ((unsigned)f2b(_b.y) << 16); \
        _g.w = f2b(_b.z) | ((unsigned)f2b(_b.w) << 16); \
        *(uint4*)(lds + (BASE) + srow*512 + (((cb*2) + _l*16) ^ swzS)) = _g; \
    } } while(0)

#define AFRAG(BASE, RT, KT) (*(const s16x8*)(lds + (BASE) + ((RT)*16 + colq)*512 + ((((KT)*64) + hi16) ^ lswz)))

#define MMPH_REG(BASE, BF, ACC) do { \
    _Pragma("unroll") \
    for (int _kt = 0; _kt < 8; ++_kt) { \
        s16x8 _a0 = AFRAG(BASE, 0, _kt), _a1 = AFRAG(BASE, 1, _kt); \
        s16x8 _a2 = AFRAG(BASE, 2, _kt), _a3 = AFRAG(BASE, 3, _kt); \
        _Pragma("unroll") \
        for (int _ct = 0; _ct < 2; ++_ct) { \
            ACC[0][_ct] = __builtin_amdgcn_mfma_f32_16x16x32_bf16(_a0, BF[_kt][_ct], ACC[0][_ct], 0, 0, 0); \
            ACC[1][_ct] = __builtin_amdgcn_mfma_f32_16x16x32_bf16(_a1, BF[_kt][_ct], ACC[1][_ct], 0, 0, 0); \
            ACC[2][_ct] = __builtin_amdgcn_mfma_f32_16x16x32_bf16(_a2, BF[_kt][_ct], ACC[2][_ct], 0, 0, 0); \
            ACC[3][_ct] = __builtin_amdgcn_mfma_f32_16x16x32_bf16(_a3, BF[_kt][_ct], ACC[3][_ct], 0, 0, 0); \
        } \
    } } while(0)

#define MMPH_STREAM(BASE, MB, ACC) do { \
    uintptr_t _o = (uintptr_t)(MB); \
    asm volatile("" : "+v"(_o)); \
    const unsigned short* _m = (const unsigned short*)_o; \
    _Pragma("unroll") \
    for (int _kt = 0; _kt < 8; ++_kt) { \
        s16x8 _b0 = *(const s16x8*)(_m + (_kt * H + c0) * 32 + kk0); \
        s16x8 _b1 = *(const s16x8*)(_m + (_kt * H + c0 + 16) * 32 + kk0); \
        s16x8 _a0 = AFRAG(BASE, 0, _kt), _a1 = AFRAG(BASE, 1, _kt); \
        s16x8 _a2 = AFRAG(BASE, 2, _kt), _a3 = AFRAG(BASE, 3, _kt); \
        ACC[0][0] = __builtin_amdgcn_mfma_f32_16x16x32_bf16(_a0, _b0, ACC[0][0], 0, 0, 0); \
        ACC[1][0] = __builtin_amdgcn_mfma_f32_16x16x32_bf16(_a1, _b0, ACC[1][0], 0, 0, 0); \
        ACC[2][0] = __builtin_amdgcn_mfma_f32_16x16x32_bf16(_a2, _b0, ACC[2][0], 0, 0, 0); \
        ACC[3][0] = __builtin_amdgcn_mfma_f32_16x16x32_bf16(_a3, _b0, ACC[3][0], 0, 0, 0); \
        ACC[0][1] = __builtin_amdgcn_mfma_f32_16x16x32_bf16(_a0, _b1, ACC[0][1], 0, 0, 0); \
        ACC[1][1] = __builtin_amdgcn_mfma_f32_16x16x32_bf16(_a1, _b1, ACC[1][1], 0, 0, 0); \
        ACC[2][1] = __builtin_amdgcn_mfma_f32_16x16x32_bf16(_a2, _b1, ACC[2][1], 0, 0, 0); \
        ACC[3][1] = __builtin_amdgcn_mfma_f32_16x16x32_bf16(_a3, _b1, ACC[3][1], 0, 0, 0); \
    } } while(0)

    if (btyp == 0) {
        // ===================== depth-0 row block =====================
        s16x8 bfL[8][2];
#pragma unroll
        for (int kt = 0; kt < 8; ++kt)
#pragma unroll
            for (int ct = 0; ct < 2; ++ct)
                bfL[kt][ct] = *(const s16x8*)(Bsw + (size_t)MSZ + (kt*H + c0 + ct*16)*32 + kk0);
        const float bb0 = bvec[c0], bb1 = bvec[c0 + 16];
        unsigned short xwr[32];
        {
            const unsigned short* xwp = sxwb + (size_t)i * CH_;
#pragma unroll
            for (int rt = 0; rt < 4; ++rt)
#pragma unroll
                for (int ct = 0; ct < 2; ++ct)
#pragma unroll
                    for (int q = 0; q < 4; ++q)
                        xwr[(rt*4+q)*2+ct] = xwp[(size_t)(rt*16 + hi*4 + q) * H + c0 + ct*16];
        }
        // pre-stage top col 0
        if (i > 0) {
            pollflag(&f0[((i-1)*T + 0)*FPAD]);
            float4 Lr[8];
            LOADR(Lr, OPTR(0, i-1, 0, 0));
            asm volatile("s_waitcnt vmcnt(0)" ::: "memory");
            WRITR(32768, Lr);
        }
        __syncthreads();

        for (int m = 0; m < T; ++m) {
            // phase C: MFMAs (top staged, left persistent) + yw issue
            unsigned short ywr[32];
            {
                const unsigned short* ywp = tywb + (size_t)m * CH_;
#pragma unroll
                for (int rt = 0; rt < 4; ++rt)
#pragma unroll
                    for (int ct = 0; ct < 2; ++ct)
#pragma unroll
                        for (int q = 0; q < 4; ++q)
                            ywr[(rt*4+q)*2+ct] = ywp[(size_t)(rt*16 + hi*4 + q) * H + c0 + ct*16];
            }
            f32x4 acc[4][2];
#pragma unroll
            for (int rt = 0; rt < 4; ++rt) { acc[rt][0] = (f32x4)(0.f); acc[rt][1] = (f32x4)(0.f); }
            if (m > 0) MMPH_REG(0, bfL, acc);
            if (i > 0) MMPH_STREAM(32768, Bsw, acc);
            __syncthreads();   // B1

            // phase E: prefetch top(m+1) + epilogue + drain
            float4 Lr[8];
            const bool pf = (i > 0) && (m + 1 < T);
            if (pf) {
                pollflag(&f0[((i-1)*T + m+1)*FPAD]);
                LOADR(Lr, OPTR(0, i-1, m+1, 0));
            }
            float* ox = OPTR(0, i, m, 0);
            float* oy = OPTR(0, i, m, 1);
#pragma unroll
            for (int rt = 0; rt < 4; ++rt)
#pragma unroll
                for (int ct = 0; ct < 2; ++ct) {
                    const float bb = ct ? bb1 : bb0;
                    const int col = c0 + ct*16;
#pragma unroll
                    for (int q = 0; q < 4; ++q) {
                        int idx = (rt*4+q)*2+ct;
                        int r = rt*16 + hi*4 + q;
                        float rec = acc[rt][ct][q] + bb;
                        float hx = tanh_fast(b2f(xwr[idx]) + rec);
                        float hy = tanh_fast(b2f(ywr[idx]) + rec);
                        __hip_atomic_store(&ox[r*H + col], hx, __ATOMIC_RELAXED, __HIP_MEMORY_SCOPE_AGENT);
                        __hip_atomic_store(&oy[r*H + col], hy, __ATOMIC_RELAXED, __HIP_MEMORY_SCOPE_AGENT);
                        *(unsigned short*)(lds + r*512 + ((col*2) ^ ((r&7)<<4))) = f2b(hx);
                    }
                }
            asm volatile("s_waitcnt vmcnt(0)" ::: "memory");
            if (pf) WRITR(32768, Lr);
            __syncthreads();   // B2
            if (tid == 0)
                __hip_atomic_store(&f0[(i*T + m)*FPAD], 1, __ATOMIC_RELAXED, __HIP_MEMORY_SCOPE_AGENT);
        }
    } else if (btyp == 1) {
        // ===================== depth-1 row block =====================
        s16x8 bfL[8][2];
#pragma unroll
        for (int kt = 0; kt < 8; ++kt)
#pragma unroll
            for (int ct = 0; ct < 2; ++ct)
                bfL[kt][ct] = *(const s16x8*)(Bsw + (size_t)3*MSZ + (kt*H + c0 + ct*16)*32 + kk0);
        const float bb0 = bvec[H + c0], bb1 = bvec[H + c0 + 16];

        if (i > 0) {
            pollflag(&f1[((i-1)*T + 0)*FPAD]);
            float4 Lr[8];
            LOADR(Lr, OPTR(1, i-1, 0, 0));
            asm volatile("s_waitcnt vmcnt(0)" ::: "memory");
            WRITR(32768, Lr);
        }
        __syncthreads();

        for (int m = 0; m < T; ++m) {
            // phase C: poll proj result, issue px/py loads, MFMAs
            pollflag(&gg[(i*T + m)*FPAD]);
            float pxr[32], pyr[32];
            {
                const float* p0s = OPTR(1, i, m, 0);
                const float* p1s = OPTR(1, i, m, 1);
#pragma unroll
                for (int rt = 0; rt < 4; ++rt)
#pragma unroll
                    for (int ct = 0; ct < 2; ++ct)
#pragma unroll
                        for (int q = 0; q < 4; ++q) {
                            int idx = (rt*4+q)*2+ct;
                            int r = rt*16 + hi*4 + q;
                            pxr[idx] = p0s[r*H + c0 + ct*16];
                            pyr[idx] = p1s[r*H + c0 + ct*16];
                        }
            }
            f32x4 acc[4][2];
#pragma unroll
            for (int rt = 0; rt < 4; ++rt) { acc[rt][0] = (f32x4)(0.f); acc[rt][1] = (f32x4)(0.f); }
            if (m > 0) MMPH_REG(0, bfL, acc);
            if (i > 0) MMPH_STREAM(32768, Bsw + (size_t)2*MSZ, acc);
            __syncthreads();   // B1

            // phase E
            float4 Lr[8];
            const bool pf = (i > 0) && (m + 1 < T);
            if (pf) {
                pollflag(&f1[((i-1)*T + m+1)*FPAD]);
                LOADR(Lr, OPTR(1, i-1, m+1, 0));
            }
            float recs[32];
            float* ox = OPTR(1, i, m, 0);
#pragma unroll
            for (int rt = 0; rt < 4; ++rt)
#pragma unroll
                for (int ct = 0; ct < 2; ++ct) {
                    const float bb = ct ? bb1 : bb0;
                    const int col = c0 + ct*16;
#pragma unroll
                    for (int q = 0; q < 4; ++q) {
                        int idx = (rt*4+q)*2+ct;
                        int r = rt*16 + hi*4 + q;
                        float rec = acc[rt][ct][q] + bb;
                        recs[idx] = rec;
                        float hx = tanh_fast(pxr[idx] + rec);
                        __hip_atomic_store(&ox[r*H + col], hx, __ATOMIC_RELAXED, __HIP_MEMORY_SCOPE_AGENT);
                        *(unsigned short*)(lds + r*512 + ((col*2) ^ ((r&7)<<4))) = f2b(hx);
                    }
                }
            asm volatile("s_waitcnt vmcnt(0)" ::: "memory");
            if (pf) WRITR(32768, Lr);
            __syncthreads();   // B2
            if (tid == 0)
                __hip_atomic_store(&f1[(i*T + m)*FPAD], 1, __ATOMIC_RELAXED, __HIP_MEMORY_SCOPE_AGENT);

            // hy1: dead-end output, after publish (drains next iter / kernel end)
            float* oy = OPTR(1, i, m, 1);
#pragma unroll
            for (int rt = 0; rt < 4; ++rt)
#pragma unroll
                for (int ct = 0; ct < 2; ++ct) {
                    const int col = c0 + ct*16;
#pragma unroll
                    for (int q = 0; q < 4; ++q) {
                        int idx = (rt*4+q)*2+ct;
                        int r = rt*16 + hi*4 + q;
                        float hy = tanh_fast(pyr[idx] + recs[idx]);
                        __hip_atomic_store(&oy[r*H + col], hy, __ATOMIC_RELAXED, __HIP_MEMORY_SCOPE_AGENT);
                    }
                }
        }
    } else {
        // ===================== projection row block (no self-chain) ==
        s16x8 bfW[8][2];
#pragma unroll
        for (int kt = 0; kt < 8; ++kt)
#pragma unroll
            for (int ct = 0; ct < 2; ++ct)
                bfW[kt][ct] = *(const s16x8*)(Bsw + (size_t)4*MSZ + (kt*H + c0 + ct*16)*32 + kk0);

        for (int m = 0; m < T; ++m) {
            pollflag(&f0[(i*T + m)*FPAD]);
            float4 La[8], Lb[8];
            LOADR(La, OPTR(0, i, m, 0));
            LOADR(Lb, OPTR(0, i, m, 1));
            asm volatile("s_waitcnt vmcnt(0)" ::: "memory");
            WRITR(0, La);
            WRITR(32768, Lb);
            __syncthreads();

            f32x4 px[4][2], py[4][2];
#pragma unroll
            for (int rt = 0; rt < 4; ++rt) { px[rt][0]=(f32x4)(0.f); px[rt][1]=(f32x4)(0.f);
                                             py[rt][0]=(f32x4)(0.f); py[rt][1]=(f32x4)(0.f); }
            MMPH_REG(0, bfW, px);
            MMPH_REG(32768, bfW, py);

            float* p0 = OPTR(1, i, m, 0);
            float* p1 = OPTR(1, i, m, 1);
#pragma unroll
            for (int rt = 0; rt < 4; ++rt)
#pragma unroll
                for (int ct = 0; ct < 2; ++ct) {
                    const int col = c0 + ct*16;
#pragma unroll
                    for (int q = 0; q < 4; ++q) {
                        int r = rt*16 + hi*4 + q;
                        __hip_atomic_store(&p0[r*H + col], px[rt][ct][q], __ATOMIC_RELAXED, __HIP_MEMORY_SCOPE_AGENT);
                        __hip_atomic_store(&p1[r*H + col], py[rt][ct][q], __ATOMIC_RELAXED, __HIP_MEMORY_SCOPE_AGENT);
                    }
                }
            asm volatile("s_waitcnt vmcnt(0)" ::: "memory");
            __syncthreads();
            if (tid == 0)
                __hip_atomic_store(&gg[(i*T + m)*FPAD], 1, __ATOMIC_RELAXED, __HIP_MEMORY_SCOPE_AGENT);
        }
    }
#undef OPTR
#undef LOADR
#undef WRITR
#undef AFRAG
#undef MMPH_REG
#undef MMPH_STREAM
}

// =================== staged fallback (round-2 structure) ===================
__global__ __launch_bounds__(64) void stage_kernel(
    const unsigned short* __restrict__ Bsw,
    const unsigned short* __restrict__ sxwb,
    const unsigned short* __restrict__ tywb,
    const float* __restrict__ bvec,
    float* __restrict__ out, int v)
{
    const int lane = threadIdx.x;
    const int cellid = blockIdx.x >> 2;
    const int stripe = blockIdx.x & 3;

    int ilo0 = (v > T-1) ? v-(T-1) : 0, ihi0 = (v < S-1) ? v : S-1;
    int n0 = (v <= S+T-2) ? (ihi0 - ilo0 + 1) : 0;
    if (n0 < 0) n0 = 0;
    int w1 = v - 1;
    int ilo1 = (w1 > T-1) ? w1-(T-1) : 0;

    int d, i, j;
    if (cellid < n0) { d = 0; i = ilo0 + cellid; j = v - i; }
    else             { d = 1; int q = cellid - n0; i = ilo1 + q; j = w1 - i; }

    const int r0   = stripe * 16;
    const int arow = r0 + (lane & 15);
    const int kk0  = (lane >> 4) * 8;
    const int colq = lane & 15;
    const int rowq = r0 + ((lane >> 4) << 2);

#define OUTB(dd,ii,jj,cc) (out + ((((size_t)(dd)*S + (ii))*T + (jj))*2 + (cc)) * (size_t)(B*H))

    if (d == 0) {
        f32x4 acc[16];
#pragma unroll
        for (int t = 0; t < 16; ++t) acc[t] = (f32x4)(0.f);
        if (i > 0) {
            const float* topM = OUTB(0, i-1, j, 0);
            const unsigned short* Bt = Bsw + 0*MSZ;
            for (int kt = 0; kt < 8; ++kt) {
                s16x8 a = make_afrag(topM, arow, kt*32 + kk0);
                const unsigned short* bp = Bt + (kt*H + colq)*32 + kk0;
#pragma unroll
                for (int ct = 0; ct < 16; ++ct)
                    acc[ct] = __builtin_amdgcn_mfma_f32_16x16x32_bf16(a, *(const s16x8*)(bp + ct*512), acc[ct], 0, 0, 0);
            }
        }
        if (j > 0) {
            const float* lftM = OUTB(0, i, j-1, 0);
            const unsigned short* Bl = Bsw + 1*MSZ;
            for (int kt = 0; kt < 8; ++kt) {
                s16x8 a = make_afrag(lftM, arow, kt*32 + kk0);
                const unsigned short* bp = Bl + (kt*H + colq)*32 + kk0;
#pragma unroll
                for (int ct = 0; ct < 16; ++ct)
                    acc[ct] = __builtin_amdgcn_mfma_f32_16x16x32_bf16(a, *(const s16x8*)(bp + ct*512), acc[ct], 0, 0, 0);
            }
        }
        const unsigned short* xwp = sxwb + (size_t)i * B * H;
        const unsigned short* ywp = tywb + (size_t)j * B * H;
        float* ox = OUTB(0, i, j, 0);
        float* oy = OUTB(0, i, j, 1);
#pragma unroll
        for (int ct = 0; ct < 16; ++ct) {
            int col = ct*16 + colq;
            float bc = bvec[col];
#pragma unroll
            for (int q = 0; q < 4; ++q) {
                int row = rowq + q;
                float rec = acc[ct][q] + bc;
                ox[row*H + col] = tanh_fast(b2f(xwp[row*H + col]) + rec);
                oy[row*H + col] = tanh_fast(b2f(ywp[row*H + col]) + rec);
            }
        }
    } else {
        const float* hx0 = OUTB(0, i, j, 0);
        const float* hy0 = OUTB(0, i, j, 1);
        const float* topM = (i > 0) ? OUTB(1, i-1, j, 0) : (const float*)0;
        const float* lftM = (j > 0) ? OUTB(1, i, j-1, 0) : (const float*)0;
        const unsigned short* BU1t = Bsw + 2*MSZ;
        const unsigned short* BU1l = Bsw + 3*MSZ;
        const unsigned short* BW1  = Bsw + 4*MSZ;
        float* ox = OUTB(1, i, j, 0);
        float* oy = OUTB(1, i, j, 1);

        for (int halfc = 0; halfc < 2; ++halfc) {
            f32x4 arr[8], axx[8], ayy[8];
#pragma unroll
            for (int t = 0; t < 8; ++t) { arr[t]=(f32x4)(0.f); axx[t]=(f32x4)(0.f); ayy[t]=(f32x4)(0.f); }
            const int bbase = halfc*4096 + colq*32 + kk0;

            for (int kt = 0; kt < 8; ++kt) {
                const int k0 = kt*32 + kk0;
                const int bofs = kt*H*32 + bbase;
                if (topM) {
                    s16x8 a = make_afrag(topM, arow, k0);
#pragma unroll
                    for (int ct = 0; ct < 8; ++ct)
                        arr[ct] = __builtin_amdgcn_mfma_f32_16x16x32_bf16(a, *(const s16x8*)(BU1t + bofs + ct*512), arr[ct], 0, 0, 0);
                }
                if (lftM) {
                    s16x8 a = make_afrag(lftM, arow, k0);
#pragma unroll
                    for (int ct = 0; ct < 8; ++ct)
                        arr[ct] = __builtin_amdgcn_mfma_f32_16x16x32_bf16(a, *(const s16x8*)(BU1l + bofs + ct*512), arr[ct], 0, 0, 0);
                }
                {
                    s16x8 a = make_afrag(hx0, arow, k0);
#pragma unroll
                    for (int ct = 0; ct < 8; ++ct)
                        axx[ct] = __builtin_amdgcn_mfma_f32_16x16x32_bf16(a, *(const s16x8*)(BW1 + bofs + ct*512), axx[ct], 0, 0, 0);
                }
                {
                    s16x8 a = make_afrag(hy0, arow, k0);
#pragma unroll
                    for (int ct = 0; ct < 8; ++ct)
                        ayy[ct] = __builtin_amdgcn_mfma_f32_16x16x32_bf16(a, *(const s16x8*)(BW1 + bofs + ct*512), ayy[ct], 0, 0, 0);
                }
            }
#pragma unroll
            for (int ct = 0; ct < 8; ++ct) {
                int col = halfc*128 + ct*16 + colq;
                float bc = bvec[H + col];
#pragma unroll
                for (int q = 0; q < 4; ++q) {
                    int row = rowq + q;
                    float rec = arr[ct][q] + bc;
                    ox[row*H + col] = tanh_fast(axx[ct][q] + rec);
                    oy[row*H + col] = tanh_fast(ayy[ct][q] + rec);
                }
            }
        }
    }
#undef OUTB
}

// ============================ host launcher ================================
extern "C" void kernel_launch(void* const* d_in, const int* in_sizes, int n_in,
                              void* d_out, int out_size, void* d_ws, size_t ws_size,
                              hipStream_t stream)
{
    const float* src = (const float*)d_in[0];
    const float* trg = (const float*)d_in[1];
    const float* W   = (const float*)d_in[2];
    const float* U   = (const float*)d_in[3];
    const float* b   = (const float*)d_in[4];
    float* out = (float*)d_out;

    const int nflags = 3 * S * T * FPAD;
    const size_t need_stage   = (size_t)5*MSZ*2 + (size_t)2*S*B*H*2;
    const size_t need_persist = need_stage + (size_t)nflags*sizeof(int);

    unsigned short* Bsw  = (unsigned short*)d_ws;
    unsigned short* sxwb = Bsw + (size_t)5*MSZ;
    unsigned short* tywb = sxwb + (size_t)S*B*H;
    int* flags = (int*)(tywb + (size_t)S*B*H);

    prep_kernel<<<(5*MSZ + 255)/256, 256, 0, stream>>>(U, W, Bsw);
    proj0b_kernel<<<2*S*B/ROWSP, 256, 0, stream>>>(src, trg, W, sxwb, tywb);

    if (ws_size >= need_persist) {
        zeroflags_kernel<<<(nflags + 255)/256, 256, 0, stream>>>(flags, nflags);
        grid_kernel<<<96, 512, 0, stream>>>(Bsw, sxwb, tywb, b, out, flags);
        return;
    }

    // -------- staged fallback --------
    for (int v = 0; v < S + T; ++v) {
        int ilo0 = (v > T-1) ? v-(T-1) : 0, ihi0 = (v < S-1) ? v : S-1;
        int n0 = (v <= S+T-2) ? (ihi0 - ilo0 + 1) : 0;
        if (n0 < 0) n0 = 0;
        int n1 = 0;
        int w1 = v - 1;
        if (w1 >= 0) {
            int ilo1 = (w1 > T-1) ? w1-(T-1) : 0, ihi1 = (w1 < S-1) ? w1 : S-1;
            n1 = ihi1 - ilo1 + 1;
        }
        stage_kernel<<<4*(n0+n1), 64, 0, stream>>>(Bsw, sxwb, tywb, b, out, v);
    }
}